// Round 18
// baseline (202.950 us; speedup 1.0000x reference)
//
#include <hip/hip_runtime.h>
#include <hip/hip_fp16.h>

#define GN 256
#define NPG 360
#define NN (GN*NPG)      // 92160
#define DEGAVG 16
#define EE (NN*DEGAVG)   // 1474560
#define EPG (NPG*DEGAVG) // 5760 edges per graph
#define EPGP (EPG + 7*NPG) // 8280: worst-case 8-padded edge count
#define HH 5
#define CC 30
#define IN_CH 11
#define NUM_GC 9
#define EPS 1e-5f

#define HLS 35   // h_l f32 row stride: 3 mod 32, coprime -> conflict-free b32 patterns
#define H16S 17  // h16 row stride in u32 (15 ch-pairs + 2 pad); norm writes bijective
#define AGS 33   // agg row stride: (n+k)%32 distinct
#define SSS 5    // ssrc/sdst row stride
#define XS 12    // x row stride (floats): 16B-aligned rows

// ---- LDS layout (bytes) ----
#define OFF_HL     0        // f32 [360*35] = 50400
#define OFF_H16    50400    // u32 [360*17] = 24480 (f16x2 mirror of h, gather-only)
#define OFF_EDGE   74880    // u32 [8280]   = 33120 (8-padded CSR)
#define OFF_UNI    108000   // 47520: EGAT {x 17280 | ssrc 7200 | sdst 7200} / GC {agg 47520}
#define OFF_ROWP   155520   // u16 [364]    = 728
#define OFF_DEG    156248   // u32 [360]    = 1440 (true degree after scatter)
#define OFF_POOL   157688   // f32 [300]    = 1200
#define OFF_FCH    158888   // f32 [56]     = 224
#define OFF_WA     159112   // f32 [112]    = 448
#define OFF_WSUM   159560   // u32 [18]     = 72
#define SMEM_TOTAL 159632

__device__ __forceinline__ float f16_to_f32(unsigned short us) {
  __half_raw r; r.x = us; return __half2float(r);
}
__device__ __forceinline__ unsigned short f32_to_f16(float f) {
  __half h = __float2half(f);
  __half_raw r = *reinterpret_cast<__half_raw*>(&h);
  return r.x;
}
__device__ __forceinline__ unsigned pack_f16x2(float a, float b) {
  __half2 h = __float22half2_rn(make_float2(a, b));
  return *reinterpret_cast<unsigned*>(&h);
}
__device__ __forceinline__ float2 unpack_f16x2(unsigned u) {
  return __half22float2(*reinterpret_cast<const __half2*>(&u));
}

// ---------- InstanceNorm (f32 in place) + f16x2 mirror + max pool: 15 ch-pairs x 32 lanes ----------
__device__ __forceinline__ void norm_pool(float* h_l, unsigned* h16_l, float* pooled_l,
                                          int layer, int tid) {
  int cp = tid >> 5, jj = tid & 31;
  if (cp < 15) {
    float va[12], vb[12];
    float sa = 0.f, s2a = 0.f, sb = 0.f, s2b = 0.f;
#pragma unroll
    for (int t = 0; t < 12; t++) {
      int i = jj + t * 32;
      float x = 0.f, y = 0.f;
      if (i < NPG) { x = h_l[i * HLS + 2 * cp]; y = h_l[i * HLS + 2 * cp + 1]; }
      va[t] = x; vb[t] = y;
      sa += x; s2a += x * x; sb += y; s2b += y * y;
    }
#pragma unroll
    for (int m = 16; m >= 1; m >>= 1) {
      sa += __shfl_xor(sa, m); s2a += __shfl_xor(s2a, m);
      sb += __shfl_xor(sb, m); s2b += __shfl_xor(s2b, m);
    }
    float ma = sa * (1.f / NPG), mb = sb * (1.f / NPG);
    float ra = rsqrtf(s2a * (1.f / NPG) - ma * ma + EPS);
    float rb = rsqrtf(s2b * (1.f / NPG) - mb * mb + EPS);
    float mxa = -1e30f, mxb = -1e30f;
#pragma unroll
    for (int t = 0; t < 12; t++) {
      int i = jj + t * 32;
      if (i < NPG) {
        float x = (va[t] - ma) * ra;
        float y = (vb[t] - mb) * rb;
        h_l[i * HLS + 2 * cp] = x;
        h_l[i * HLS + 2 * cp + 1] = y;
        h16_l[i * H16S + cp] = pack_f16x2(x, y);   // banks (17i+cp): bijective, free
        mxa = fmaxf(mxa, x); mxb = fmaxf(mxb, y);
      }
    }
#pragma unroll
    for (int m = 16; m >= 1; m >>= 1) {
      mxa = fmaxf(mxa, __shfl_xor(mxa, m));
      mxb = fmaxf(mxb, __shfl_xor(mxb, m));
    }
    if (jj == 0) {
      pooled_l[layer * CC + 2 * cp] = mxa;
      pooled_l[layer * CC + 2 * cp + 1] = mxb;
    }
  }
}

// ---------- GraphConv matmul half (compile-time channel base -> scalar weight loads) ----------
template <int CB>
__device__ __forceinline__ void mm_half(int n, const float* h_l, const float* agg_l,
                                        const float* Wr, const float* Wn, const float* bs,
                                        float* acc) {
#pragma unroll
  for (int c = 0; c < 15; c++) acc[c] = bs[CB + c];
  const float* hr = h_l + n * HLS;
  const float* ar = agg_l + n * AGS;
#pragma unroll
  for (int k = 0; k < CC; k++) {
    float hk = hr[k];
#pragma unroll
    for (int c = 0; c < 15; c++) acc[c] = fmaf(hk, Wr[k * CC + CB + c], acc[c]);
  }
#pragma unroll
  for (int k = 0; k < CC; k++) {
    float ak = ar[k];
#pragma unroll
    for (int c = 0; c < 15; c++) acc[c] = fmaf(ak, Wn[k * CC + CB + c], acc[c]);
  }
}

// ---------- mega-kernel ----------
__global__ __launch_bounds__(1024, 4) void k_mega(
    const float* __restrict__ x, const int* __restrict__ ei, const float* __restrict__ eattr,
    const float* __restrict__ egw, const float* __restrict__ att_s,
    const float* __restrict__ att_d, const float* __restrict__ att_e,
    const float* __restrict__ wroot, const float* __restrict__ wnbr,
    const float* __restrict__ gcb,
    const float* __restrict__ fc1w, const float* __restrict__ fc1b,
    const float* __restrict__ fc2w, const float* __restrict__ fc2b,
    float* __restrict__ out) {
  __shared__ __align__(16) unsigned char smem[SMEM_TOTAL];
  float*          h_l     = (float*)(smem + OFF_HL);
  unsigned*       h16_l   = (unsigned*)(smem + OFF_H16);
  unsigned*       edge_l  = (unsigned*)(smem + OFF_EDGE);
  float*          x_l     = (float*)(smem + OFF_UNI);
  float*          ssrc_l  = (float*)(smem + OFF_UNI) + NPG * XS;
  float*          sdst_l  = (float*)(smem + OFF_UNI) + NPG * XS + NPG * SSS;
  float*          agg_l   = (float*)(smem + OFF_UNI);          // GC-phase alias
  unsigned short* rowp_l  = (unsigned short*)(smem + OFF_ROWP);
  unsigned*       deg_l   = (unsigned*)(smem + OFF_DEG);
  float*          pooled_l= (float*)(smem + OFF_POOL);
  float*          fch     = (float*)(smem + OFF_FCH);
  float*          wa_l    = (float*)(smem + OFF_WA);
  unsigned*       wsum    = (unsigned*)(smem + OFF_WSUM);

  const int g = blockIdx.x, tid = threadIdx.x;
  const int nb = g * NPG;
  const int ebase = g * EPG;            // edges are graph-contiguous by construction
  const int lane = tid & 63, wid = tid >> 6;

  // ---- P0: zero deg + edge region + h16 (pads must stay 0), stage x ----
  for (int i = tid; i < NPG; i += 1024) deg_l[i] = 0u;
  for (int i = tid; i < EPGP; i += 1024) edge_l[i] = 0u;
  for (int i = tid; i < NPG * H16S; i += 1024) h16_l[i] = 0u;
  for (int it = tid; it < NPG * XS; it += 1024) {
    int n = it / XS, i = it - n * XS;
    x_l[it] = (i < IN_CH) ? x[(size_t)(nb + n) * IN_CH + i] : 0.f;
  }
  __syncthreads();

  // ---- P1: degree histogram (LDS atomics) + wa precontraction ----
  for (int e = tid; e < EPG; e += 1024) {
    int d = ei[EE + ebase + e] - nb;
    atomicAdd(&deg_l[d], 1u);
  }
  if (tid < 110) {
    int half = tid >= 55;
    int idx = tid - half * 55;
    int i = idx / 5, h = idx - i * 5;
    const float* av = half ? att_d : att_s;
    float s = 0.f;
#pragma unroll
    for (int c = 0; c < CC; c++) s += egw[(i * HH + h) * CC + c] * av[h * CC + c];
    wa_l[tid] = s;
  }
  __syncthreads();

  // ---- P2: block scan of 8-PADDED degrees -> rowp_l (8-aligned segments) ----
  {
    unsigned v = (tid < NPG) ? ((deg_l[tid] + 7u) & ~7u) : 0u;
#pragma unroll
    for (int off = 1; off < 64; off <<= 1) {
      unsigned t = (unsigned)__shfl_up((int)v, off);
      if (lane >= off) v += t;
    }
    if (lane == 63) wsum[wid] = v;
    __syncthreads();
    if (tid == 0) {
      unsigned run = 0;
      for (int i = 0; i < 16; i++) { unsigned t = wsum[i]; wsum[i] = run; run += t; }
    }
    __syncthreads();
    if (tid < NPG) rowp_l[tid + 1] = (unsigned short)(v + wsum[wid]);
    if (tid == 0) rowp_l[0] = 0;
    if (tid < NPG) deg_l[tid] = 0u;     // becomes scatter cursor (ends = TRUE degree)
  }
  __syncthreads();

  // ---- P3: scatter edges into padded CSR (raw src | eattr_f16) + ssrc/sdst dots ----
  for (int e = tid; e < EPG; e += 1024) {
    int s = ei[ebase + e] - nb;
    int d = ei[EE + ebase + e] - nb;
    float ea = eattr[ebase + e];
    unsigned pos = (unsigned)rowp_l[d] + atomicAdd(&deg_l[d], 1u);
    edge_l[pos] = (unsigned)s | ((unsigned)f32_to_f16(ea) << 16);
  }
  if (tid < NPG) {
    float xi[IN_CH];
#pragma unroll
    for (int i = 0; i < IN_CH; i++) xi[i] = x_l[tid * XS + i];
#pragma unroll
    for (int h = 0; h < HH; h++) {
      float s1 = 0.f, s2 = 0.f;
#pragma unroll
      for (int i = 0; i < IN_CH; i++) {
        s1 = fmaf(xi[i], wa_l[i * HH + h], s1);
        s2 = fmaf(xi[i], wa_l[55 + i * HH + h], s2);
      }
      ssrc_l[tid * SSS + h] = s1;
      sdst_l[tid * SSS + h] = s2;
    }
  }
  __syncthreads();

  // ---- P4: EGAT thread-per-node over TRUE degree (padding must not enter softmax) ----
  if (tid < NPG) {
    const int n = tid;
    const int b = rowp_l[n];
    const int en = b + (int)deg_l[n];          // true edges only
    float sd[HH], ae[HH];
#pragma unroll
    for (int h = 0; h < HH; h++) { sd[h] = sdst_l[n * SSS + h]; ae[h] = att_e[h]; }
    float dn[HH];
#pragma unroll
    for (int h = 0; h < HH; h++) dn[h] = 0.f;
    // pass 1: denominators; b is 8-aligned -> uint2 edge loads
    int p = b;
    for (; p + 1 < en; p += 2) {
      const uint2 U = *(const uint2*)&edge_l[p];
      int sa_ = U.x & 0xffffu, sb_ = U.y & 0xffffu;
      float eaa = f16_to_f32((unsigned short)(U.x >> 16));
      float eab = f16_to_f32((unsigned short)(U.y >> 16));
      const float* sra = ssrc_l + sa_ * SSS;
      const float* srb = ssrc_l + sb_ * SSS;
#pragma unroll
      for (int h = 0; h < HH; h++) {
        float la = sra[h] + sd[h] + eaa * ae[h];
        float lb = srb[h] + sd[h] + eab * ae[h];
        la = la > 0.f ? la : 0.2f * la;
        lb = lb > 0.f ? lb : 0.2f * lb;
        dn[h] += __expf(la) + __expf(lb);
      }
    }
    if (p < en) {
      unsigned u = edge_l[p];
      int s = u & 0xffffu;
      float ea = f16_to_f32((unsigned short)(u >> 16));
      const float* sr = ssrc_l + s * SSS;
#pragma unroll
      for (int h = 0; h < HH; h++) {
        float lg = sr[h] + sd[h] + ea * ae[h];
        lg = lg > 0.f ? lg : 0.2f * lg;
        dn[h] += __expf(lg);
      }
    }
    float rdn[HH];
#pragma unroll
    for (int h = 0; h < HH; h++) rdn[h] = 1.f / (dn[h] + 1e-16f);
    float gg[55];
#pragma unroll
    for (int k = 0; k < 55; k++) gg[k] = 0.f;
    for (p = b; p < en; p++) {                // pass 2: alpha, 11-dim gather, edge rewrite
      unsigned u = edge_l[p];
      int s = u & 0xffffu;
      float ea = f16_to_f32((unsigned short)(u >> 16));
      const float* sr = ssrc_l + s * SSS;
      const float* xr = x_l + s * XS;
      const float4 xv0 = *(const float4*)(xr);
      const float4 xv1 = *(const float4*)(xr + 4);
      const float4 xv2 = *(const float4*)(xr + 8);
      const float xi[IN_CH] = {xv0.x, xv0.y, xv0.z, xv0.w, xv1.x, xv1.y, xv1.z, xv1.w,
                               xv2.x, xv2.y, xv2.z};
      float ews = 0.f;
#pragma unroll
      for (int h = 0; h < HH; h++) {
        float lg = sr[h] + sd[h] + ea * ae[h];
        lg = lg > 0.f ? lg : 0.2f * lg;
        float a = __expf(lg) * rdn[h];
        ews += a;
#pragma unroll
        for (int i = 0; i < IN_CH; i++) gg[h * IN_CH + i] = fmaf(a, xi[i], gg[h * IN_CH + i]);
      }
      // rewrite edge: premultiplied h16 BYTE offset (s*68 < 65536) | f16(mean alpha)
      edge_l[p] = (unsigned)(s * (H16S * 4)) | ((unsigned)f32_to_f16(ews * 0.2f) << 16);
    }
    // h = 0.2 * sum_h g_h . W_h  (uniform scalar weight loads)
#pragma unroll
    for (int half = 0; half < 2; half++) {
      float acc[15];
#pragma unroll
      for (int c = 0; c < 15; c++) acc[c] = 0.f;
#pragma unroll
      for (int i = 0; i < IN_CH; i++) {
#pragma unroll
        for (int h = 0; h < HH; h++) {
          float gv = gg[h * IN_CH + i];
          const float* wr = egw + (i * HH + h) * CC + half * 15;
#pragma unroll
          for (int c = 0; c < 15; c++) acc[c] = fmaf(gv, wr[c], acc[c]);
        }
      }
#pragma unroll
      for (int c = 0; c < 15; c++) h_l[n * HLS + half * 15 + c] = 0.2f * acc[c];
    }
  }
  __syncthreads();

  // ---- P5: norm0 + h16 mirror + pooled[0] ----
  norm_pool(h_l, h16_l, pooled_l, 0, tid);
  __syncthreads();

  // ---- GC stack ----
  const int es = lane >> 4;          // edge-quad slot 0..3
  const int cp4 = (lane & 15) << 2;  // ch-pair byte offset (cp=15 reads zero pad)
  const char* h16b = (const char*)h16_l;
#pragma unroll 1
  for (int l = 0; l < NUM_GC; l++) {
    // gather: wave per node. Per 16 padded edges: ONE uint4 edge instr (16 consecutive
    // words, conflict-free) + 4 f16x2 h instrs (4 random rows x 16-bank spans, ~2-way).
    // Padding words are 0 -> w=0, reads row 0: contributes nothing.
    for (int n = wid; n < NPG; n += 16) {
      int b = rowp_l[n], en = rowp_l[n + 1];   // padded extent, multiple of 8
      float a0 = 0.f, a1 = 0.f;
      int p = b;
      for (; p + 16 <= en; p += 16) {
        const uint4 E = *(const uint4*)&edge_l[p + 4 * es];
        float2 v0 = unpack_f16x2(*(const unsigned*)(h16b + (E.x & 0xffffu) + cp4));
        float2 v1 = unpack_f16x2(*(const unsigned*)(h16b + (E.y & 0xffffu) + cp4));
        float2 v2 = unpack_f16x2(*(const unsigned*)(h16b + (E.z & 0xffffu) + cp4));
        float2 v3 = unpack_f16x2(*(const unsigned*)(h16b + (E.w & 0xffffu) + cp4));
        float w0 = f16_to_f32((unsigned short)(E.x >> 16));
        float w1 = f16_to_f32((unsigned short)(E.y >> 16));
        float w2 = f16_to_f32((unsigned short)(E.z >> 16));
        float w3 = f16_to_f32((unsigned short)(E.w >> 16));
        a0 = fmaf(w0, v0.x, a0); a1 = fmaf(w0, v0.y, a1);
        a0 = fmaf(w1, v1.x, a0); a1 = fmaf(w1, v1.y, a1);
        a0 = fmaf(w2, v2.x, a0); a1 = fmaf(w2, v2.y, a1);
        a0 = fmaf(w3, v3.x, a0); a1 = fmaf(w3, v3.y, a1);
      }
      if (p < en) {                            // 8-edge tail: uint2 per quad-slot
        const uint2 E = *(const uint2*)&edge_l[p + 2 * es];
        float2 v0 = unpack_f16x2(*(const unsigned*)(h16b + (E.x & 0xffffu) + cp4));
        float2 v1 = unpack_f16x2(*(const unsigned*)(h16b + (E.y & 0xffffu) + cp4));
        float w0 = f16_to_f32((unsigned short)(E.x >> 16));
        float w1 = f16_to_f32((unsigned short)(E.y >> 16));
        a0 = fmaf(w0, v0.x, a0); a1 = fmaf(w0, v0.y, a1);
        a0 = fmaf(w1, v1.x, a0); a1 = fmaf(w1, v1.y, a1);
      }
      a0 += __shfl_xor(a0, 16); a1 += __shfl_xor(a1, 16);
      a0 += __shfl_xor(a0, 32); a1 += __shfl_xor(a1, 32);
      if (lane < 15) {
        agg_l[n * AGS + 2 * lane] = a0;
        agg_l[n * AGS + 2 * lane + 1] = a1;
      }
    }
    __syncthreads();
    // matmul halves: compute (reads) -> barrier -> write (avoids cross-half RW race)
    const float* Wr = wroot + l * CC * CC;
    const float* Wn = wnbr + l * CC * CC;
    const float* bs = gcb + l * CC;
    float acc[15];
    int n = -1, cb = 0;
    if (tid < NPG) { n = tid; cb = 0; mm_half<0>(n, h_l, agg_l, Wr, Wn, bs, acc); }
    else if (tid >= 512 && tid < 512 + NPG) { n = tid - 512; cb = 15; mm_half<15>(n, h_l, agg_l, Wr, Wn, bs, acc); }
    __syncthreads();
    if (n >= 0) {
#pragma unroll
      for (int c = 0; c < 15; c++) h_l[n * HLS + cb + c] = acc[c];
    }
    __syncthreads();
    norm_pool(h_l, h16_l, pooled_l, l + 1, tid);
    __syncthreads();
  }

  // ---- final MLP ----
  if (tid < 50) {
    float a = fc1b[tid];
    for (int i = 0; i < 10 * CC; i++) a = fmaf(pooled_l[i], fc1w[i * 50 + tid], a);
    fch[tid] = fmaxf(a, 0.f);
  }
  __syncthreads();
  if (tid < 2) {
    float o = fc2b[tid];
#pragma unroll
    for (int j = 0; j < 50; j++) o = fmaf(fch[j], fc2w[j * 2 + tid], o);
    out[g * 2 + tid] = o;
  }
}

extern "C" void kernel_launch(void* const* d_in, const int* in_sizes, int n_in,
                              void* d_out, int out_size, void* d_ws, size_t ws_size,
                              hipStream_t stream) {
  (void)d_ws; (void)ws_size; (void)in_sizes; (void)n_in; (void)out_size;
  const float* x     = (const float*)d_in[0];
  const int*   ei    = (const int*)d_in[1];
  const float* eattr = (const float*)d_in[2];
  const float* egw   = (const float*)d_in[4];
  const float* att_s = (const float*)d_in[5];
  const float* att_d = (const float*)d_in[6];
  const float* att_e = (const float*)d_in[7];
  const float* wroot = (const float*)d_in[8];
  const float* wnbr  = (const float*)d_in[9];
  const float* gcb   = (const float*)d_in[10];
  const float* fc1w  = (const float*)d_in[11];
  const float* fc1b  = (const float*)d_in[12];
  const float* fc2w  = (const float*)d_in[13];
  const float* fc2b  = (const float*)d_in[14];
  float* out = (float*)d_out;

  k_mega<<<GN, 1024, 0, stream>>>(x, ei, eattr, egw, att_s, att_d, att_e,
                                  wroot, wnbr, gcb, fc1w, fc1b, fc2w, fc2b, out);
}

// Round 19
// 191.616 us; speedup vs baseline: 1.0592x; 1.0592x over previous
//
#include <hip/hip_runtime.h>
#include <hip/hip_fp16.h>

#define GN 256
#define NPG 360
#define NN (GN*NPG)      // 92160
#define DEGAVG 16
#define EE (NN*DEGAVG)   // 1474560
#define EPG (NPG*DEGAVG) // 5760 edges per graph
#define EPGP (EPG + 7*NPG) // 8280: worst-case 8-padded edge count
#define HH 5
#define CC 30
#define IN_CH 11
#define NUM_GC 9
#define EPS 1e-5f

#define HLS 35   // h_l f32 row stride: 3 mod 32, coprime -> conflict-free b32 patterns
#define AGS 33   // agg row stride: (n+k)%32 distinct
#define SSS 5    // ssrc/sdst row stride
#define XS 12    // x row stride (floats): 16B-aligned rows

// ---- LDS layout (bytes) ----
#define OFF_HL     0        // float[360*35] = 50400
#define OFF_EDGE   50400    // uint [8280]   = 33120 (8-padded CSR)
#define OFF_UNI    83520    // 47520: EGAT {x 17280 | ssrc 7200 | sdst 7200} / GC {agg 47520}
#define OFF_ROWP   131040   // u16  [364]    = 728
#define OFF_DEG    131768   // uint [360]    = 1440 (true degree after scatter)
#define OFF_POOL   133208   // float[300]    = 1200
#define OFF_FCH    134408   // float[56]     = 224
#define OFF_WA     134632   // float[112]    = 448
#define OFF_WSUM   135080   // uint [18]     = 72
#define SMEM_TOTAL 135152

__device__ __forceinline__ float f16_to_f32(unsigned short us) {
  __half_raw r; r.x = us; return __half2float(r);
}
__device__ __forceinline__ unsigned short f32_to_f16(float f) {
  __half h = __float2half(f);
  __half_raw r = *reinterpret_cast<__half_raw*>(&h);
  return r.x;
}

// ---------- InstanceNorm (in place, f32) + per-graph max pool: 30 ch x 32 lanes ----------
__device__ __forceinline__ void norm_pool(float* h_l, float* pooled_l, int layer, int tid) {
  int c = tid >> 5, jj = tid & 31;
  if (c < CC) {
    float va[12];
    float s = 0.f, s2 = 0.f;
#pragma unroll
    for (int t = 0; t < 12; t++) {
      int i = jj + t * 32;
      float v = (i < NPG) ? h_l[i * HLS + c] : 0.f;
      va[t] = v; s += v; s2 += v * v;
    }
#pragma unroll
    for (int m = 16; m >= 1; m >>= 1) { s += __shfl_xor(s, m); s2 += __shfl_xor(s2, m); }
    float mean = s * (1.f / NPG);
    float rs = rsqrtf(s2 * (1.f / NPG) - mean * mean + EPS);
    float mx = -1e30f;
#pragma unroll
    for (int t = 0; t < 12; t++) {
      int i = jj + t * 32;
      if (i < NPG) {
        float v = (va[t] - mean) * rs;
        h_l[i * HLS + c] = v;
        mx = fmaxf(mx, v);
      }
    }
#pragma unroll
    for (int m = 16; m >= 1; m >>= 1) mx = fmaxf(mx, __shfl_xor(mx, m));
    if (jj == 0) pooled_l[layer * CC + c] = mx;
  }
}

// ---------- GraphConv matmul half (compile-time channel base -> scalar weight loads) ----------
template <int CB>
__device__ __forceinline__ void mm_half(int n, const float* h_l, const float* agg_l,
                                        const float* Wr, const float* Wn, const float* bs,
                                        float* acc) {
#pragma unroll
  for (int c = 0; c < 15; c++) acc[c] = bs[CB + c];
  const float* hr = h_l + n * HLS;
  const float* ar = agg_l + n * AGS;
#pragma unroll
  for (int k = 0; k < CC; k++) {
    float hk = hr[k];
#pragma unroll
    for (int c = 0; c < 15; c++) acc[c] = fmaf(hk, Wr[k * CC + CB + c], acc[c]);
  }
#pragma unroll
  for (int k = 0; k < CC; k++) {
    float ak = ar[k];
#pragma unroll
    for (int c = 0; c < 15; c++) acc[c] = fmaf(ak, Wn[k * CC + CB + c], acc[c]);
  }
}

// ---------- mega-kernel ----------
__global__ __launch_bounds__(1024, 4) void k_mega(
    const float* __restrict__ x, const int* __restrict__ ei, const float* __restrict__ eattr,
    const float* __restrict__ egw, const float* __restrict__ att_s,
    const float* __restrict__ att_d, const float* __restrict__ att_e,
    const float* __restrict__ wroot, const float* __restrict__ wnbr,
    const float* __restrict__ gcb,
    const float* __restrict__ fc1w, const float* __restrict__ fc1b,
    const float* __restrict__ fc2w, const float* __restrict__ fc2b,
    float* __restrict__ out) {
  __shared__ __align__(16) unsigned char smem[SMEM_TOTAL];
  float*          h_l     = (float*)(smem + OFF_HL);
  unsigned*       edge_l  = (unsigned*)(smem + OFF_EDGE);
  float*          x_l     = (float*)(smem + OFF_UNI);
  float*          ssrc_l  = (float*)(smem + OFF_UNI) + NPG * XS;
  float*          sdst_l  = (float*)(smem + OFF_UNI) + NPG * XS + NPG * SSS;
  float*          agg_l   = (float*)(smem + OFF_UNI);          // GC-phase alias
  unsigned short* rowp_l  = (unsigned short*)(smem + OFF_ROWP);
  unsigned*       deg_l   = (unsigned*)(smem + OFF_DEG);
  float*          pooled_l= (float*)(smem + OFF_POOL);
  float*          fch     = (float*)(smem + OFF_FCH);
  float*          wa_l    = (float*)(smem + OFF_WA);
  unsigned*       wsum    = (unsigned*)(smem + OFF_WSUM);

  const int g = blockIdx.x, tid = threadIdx.x;
  const int nb = g * NPG;
  const int ebase = g * EPG;            // edges are graph-contiguous by construction
  const int lane = tid & 63, wid = tid >> 6;

  // ---- P0: zero deg + FULL edge region (padding words must be 0), stage x ----
  for (int i = tid; i < NPG; i += 1024) deg_l[i] = 0u;
  for (int i = tid; i < EPGP; i += 1024) edge_l[i] = 0u;
  for (int it = tid; it < NPG * XS; it += 1024) {
    int n = it / XS, i = it - n * XS;
    x_l[it] = (i < IN_CH) ? x[(size_t)(nb + n) * IN_CH + i] : 0.f;
  }
  __syncthreads();

  // ---- P1: degree histogram (LDS atomics) + wa precontraction ----
  for (int e = tid; e < EPG; e += 1024) {
    int d = ei[EE + ebase + e] - nb;
    atomicAdd(&deg_l[d], 1u);
  }
  if (tid < 110) {
    int half = tid >= 55;
    int idx = tid - half * 55;
    int i = idx / 5, h = idx - i * 5;
    const float* av = half ? att_d : att_s;
    float s = 0.f;
#pragma unroll
    for (int c = 0; c < CC; c++) s += egw[(i * HH + h) * CC + c] * av[h * CC + c];
    wa_l[tid] = s;
  }
  __syncthreads();

  // ---- P2: block scan of 8-PADDED degrees -> rowp_l (8-aligned segments) ----
  {
    unsigned v = (tid < NPG) ? ((deg_l[tid] + 7u) & ~7u) : 0u;
#pragma unroll
    for (int off = 1; off < 64; off <<= 1) {
      unsigned t = (unsigned)__shfl_up((int)v, off);
      if (lane >= off) v += t;
    }
    if (lane == 63) wsum[wid] = v;
    __syncthreads();
    if (tid == 0) {
      unsigned run = 0;
      for (int i = 0; i < 16; i++) { unsigned t = wsum[i]; wsum[i] = run; run += t; }
    }
    __syncthreads();
    if (tid < NPG) rowp_l[tid + 1] = (unsigned short)(v + wsum[wid]);
    if (tid == 0) rowp_l[0] = 0;
    if (tid < NPG) deg_l[tid] = 0u;     // becomes scatter cursor (ends = TRUE degree)
  }
  __syncthreads();

  // ---- P3: scatter edges into padded CSR (raw src | eattr_f16) + ssrc/sdst dots ----
  for (int e = tid; e < EPG; e += 1024) {
    int s = ei[ebase + e] - nb;
    int d = ei[EE + ebase + e] - nb;
    float ea = eattr[ebase + e];
    unsigned pos = (unsigned)rowp_l[d] + atomicAdd(&deg_l[d], 1u);
    edge_l[pos] = (unsigned)s | ((unsigned)f32_to_f16(ea) << 16);
  }
  if (tid < NPG) {
    float xi[IN_CH];
#pragma unroll
    for (int i = 0; i < IN_CH; i++) xi[i] = x_l[tid * XS + i];
#pragma unroll
    for (int h = 0; h < HH; h++) {
      float s1 = 0.f, s2 = 0.f;
#pragma unroll
      for (int i = 0; i < IN_CH; i++) {
        s1 = fmaf(xi[i], wa_l[i * HH + h], s1);
        s2 = fmaf(xi[i], wa_l[55 + i * HH + h], s2);
      }
      ssrc_l[tid * SSS + h] = s1;
      sdst_l[tid * SSS + h] = s2;
    }
  }
  __syncthreads();

  // ---- P4: EGAT thread-per-node over TRUE degree (padding must not enter softmax) ----
  if (tid < NPG) {
    const int n = tid;
    const int b = rowp_l[n];
    const int en = b + (int)deg_l[n];          // true edges only
    float sd[HH], ae[HH];
#pragma unroll
    for (int h = 0; h < HH; h++) { sd[h] = sdst_l[n * SSS + h]; ae[h] = att_e[h]; }
    float dn[HH];
#pragma unroll
    for (int h = 0; h < HH; h++) dn[h] = 0.f;
    // pass 1: denominators; b is 8-aligned -> uint2 edge loads
    int p = b;
    for (; p + 1 < en; p += 2) {
      const uint2 U = *(const uint2*)&edge_l[p];
      int sa_ = U.x & 0xffffu, sb_ = U.y & 0xffffu;
      float eaa = f16_to_f32((unsigned short)(U.x >> 16));
      float eab = f16_to_f32((unsigned short)(U.y >> 16));
      const float* sra = ssrc_l + sa_ * SSS;
      const float* srb = ssrc_l + sb_ * SSS;
#pragma unroll
      for (int h = 0; h < HH; h++) {
        float la = sra[h] + sd[h] + eaa * ae[h];
        float lb = srb[h] + sd[h] + eab * ae[h];
        la = la > 0.f ? la : 0.2f * la;
        lb = lb > 0.f ? lb : 0.2f * lb;
        dn[h] += __expf(la) + __expf(lb);
      }
    }
    if (p < en) {
      unsigned u = edge_l[p];
      int s = u & 0xffffu;
      float ea = f16_to_f32((unsigned short)(u >> 16));
      const float* sr = ssrc_l + s * SSS;
#pragma unroll
      for (int h = 0; h < HH; h++) {
        float lg = sr[h] + sd[h] + ea * ae[h];
        lg = lg > 0.f ? lg : 0.2f * lg;
        dn[h] += __expf(lg);
      }
    }
    float rdn[HH];
#pragma unroll
    for (int h = 0; h < HH; h++) rdn[h] = 1.f / (dn[h] + 1e-16f);
    float gg[55];
#pragma unroll
    for (int k = 0; k < 55; k++) gg[k] = 0.f;
    for (p = b; p < en; p++) {                // pass 2: alpha, 11-dim gather, edge rewrite
      unsigned u = edge_l[p];
      int s = u & 0xffffu;
      float ea = f16_to_f32((unsigned short)(u >> 16));
      const float* sr = ssrc_l + s * SSS;
      const float* xr = x_l + s * XS;
      const float4 xv0 = *(const float4*)(xr);
      const float4 xv1 = *(const float4*)(xr + 4);
      const float4 xv2 = *(const float4*)(xr + 8);
      const float xi[IN_CH] = {xv0.x, xv0.y, xv0.z, xv0.w, xv1.x, xv1.y, xv1.z, xv1.w,
                               xv2.x, xv2.y, xv2.z};
      float ews = 0.f;
#pragma unroll
      for (int h = 0; h < HH; h++) {
        float lg = sr[h] + sd[h] + ea * ae[h];
        lg = lg > 0.f ? lg : 0.2f * lg;
        float a = __expf(lg) * rdn[h];
        ews += a;
#pragma unroll
        for (int i = 0; i < IN_CH; i++) gg[h * IN_CH + i] = fmaf(a, xi[i], gg[h * IN_CH + i]);
      }
      // rewrite edge: premultiplied h_l BYTE offset (s*140 < 65536) | f16(mean alpha)
      edge_l[p] = (unsigned)(s * (HLS * 4)) | ((unsigned)f32_to_f16(ews * 0.2f) << 16);
    }
    // h = 0.2 * sum_h g_h . W_h  (uniform scalar weight loads)
#pragma unroll
    for (int half = 0; half < 2; half++) {
      float acc[15];
#pragma unroll
      for (int c = 0; c < 15; c++) acc[c] = 0.f;
#pragma unroll
      for (int i = 0; i < IN_CH; i++) {
#pragma unroll
        for (int h = 0; h < HH; h++) {
          float gv = gg[h * IN_CH + i];
          const float* wr = egw + (i * HH + h) * CC + half * 15;
#pragma unroll
          for (int c = 0; c < 15; c++) acc[c] = fmaf(gv, wr[c], acc[c]);
        }
      }
#pragma unroll
      for (int c = 0; c < 15; c++) h_l[n * HLS + half * 15 + c] = 0.2f * acc[c];
    }
  }
  __syncthreads();

  // ---- P5: norm0 + pooled[0] ----
  norm_pool(h_l, pooled_l, 0, tid);
  __syncthreads();

  // ---- GC stack ----
  const int es = lane >> 5;          // edge-quad slot 0/1
  const int cg4 = (lane & 31) << 2;  // channel byte offset (ch 30,31 dummy)
  const char* hb = (const char*)h_l;
#pragma unroll 1
  for (int l = 0; l < NUM_GC; l++) {
    // gather: wave per node. Per 8 padded edges: ONE uint4 edge read (b128,
    // 2 addrs/wave) + 4 h b32 reads (2 random rows x 32 banks each = 2-way free).
    // Padding words are 0 -> fma(0, h[0], a) contributes nothing.
    for (int n = wid; n < NPG; n += 16) {
      int b = rowp_l[n], en = rowp_l[n + 1];   // padded extent, multiple of 8
      float a0 = 0.f, a1 = 0.f, a2 = 0.f, a3 = 0.f;
      int p = b + 4 * es;
      for (; p + 8 < en; p += 16) {            // 16-edge blocks: 2 uint4 in flight
        const uint4 Ea = *(const uint4*)&edge_l[p];
        const uint4 Eb = *(const uint4*)&edge_l[p + 8];
        float h0 = *(const float*)(hb + (Ea.x & 0xffffu) + cg4);
        float h1 = *(const float*)(hb + (Ea.y & 0xffffu) + cg4);
        float h2 = *(const float*)(hb + (Ea.z & 0xffffu) + cg4);
        float h3 = *(const float*)(hb + (Ea.w & 0xffffu) + cg4);
        float h4 = *(const float*)(hb + (Eb.x & 0xffffu) + cg4);
        float h5 = *(const float*)(hb + (Eb.y & 0xffffu) + cg4);
        float h6 = *(const float*)(hb + (Eb.z & 0xffffu) + cg4);
        float h7 = *(const float*)(hb + (Eb.w & 0xffffu) + cg4);
        a0 = fmaf(f16_to_f32((unsigned short)(Ea.x >> 16)), h0, a0);
        a1 = fmaf(f16_to_f32((unsigned short)(Ea.y >> 16)), h1, a1);
        a2 = fmaf(f16_to_f32((unsigned short)(Ea.z >> 16)), h2, a2);
        a3 = fmaf(f16_to_f32((unsigned short)(Ea.w >> 16)), h3, a3);
        a0 = fmaf(f16_to_f32((unsigned short)(Eb.x >> 16)), h4, a0);
        a1 = fmaf(f16_to_f32((unsigned short)(Eb.y >> 16)), h5, a1);
        a2 = fmaf(f16_to_f32((unsigned short)(Eb.z >> 16)), h6, a2);
        a3 = fmaf(f16_to_f32((unsigned short)(Eb.w >> 16)), h7, a3);
      }
      if (p < en) {                            // 8-edge tail: one uint4 per half
        const uint4 E = *(const uint4*)&edge_l[p];
        float h0 = *(const float*)(hb + (E.x & 0xffffu) + cg4);
        float h1 = *(const float*)(hb + (E.y & 0xffffu) + cg4);
        float h2 = *(const float*)(hb + (E.z & 0xffffu) + cg4);
        float h3 = *(const float*)(hb + (E.w & 0xffffu) + cg4);
        a0 = fmaf(f16_to_f32((unsigned short)(E.x >> 16)), h0, a0);
        a1 = fmaf(f16_to_f32((unsigned short)(E.y >> 16)), h1, a1);
        a2 = fmaf(f16_to_f32((unsigned short)(E.z >> 16)), h2, a2);
        a3 = fmaf(f16_to_f32((unsigned short)(E.w >> 16)), h3, a3);
      }
      float a = (a0 + a1) + (a2 + a3);
      a += __shfl_xor(a, 32);
      if (lane < CC) agg_l[n * AGS + lane] = a;
    }
    __syncthreads();
    // matmul halves: compute (reads) -> barrier -> write (avoids cross-half RW race)
    const float* Wr = wroot + l * CC * CC;
    const float* Wn = wnbr + l * CC * CC;
    const float* bs = gcb + l * CC;
    float acc[15];
    int n = -1, cb = 0;
    if (tid < NPG) { n = tid; cb = 0; mm_half<0>(n, h_l, agg_l, Wr, Wn, bs, acc); }
    else if (tid >= 512 && tid < 512 + NPG) { n = tid - 512; cb = 15; mm_half<15>(n, h_l, agg_l, Wr, Wn, bs, acc); }
    __syncthreads();
    if (n >= 0) {
#pragma unroll
      for (int c = 0; c < 15; c++) h_l[n * HLS + cb + c] = acc[c];
    }
    __syncthreads();
    norm_pool(h_l, pooled_l, l + 1, tid);
    __syncthreads();
  }

  // ---- final MLP ----
  if (tid < 50) {
    float a = fc1b[tid];
    for (int i = 0; i < 10 * CC; i++) a = fmaf(pooled_l[i], fc1w[i * 50 + tid], a);
    fch[tid] = fmaxf(a, 0.f);
  }
  __syncthreads();
  if (tid < 2) {
    float o = fc2b[tid];
#pragma unroll
    for (int j = 0; j < 50; j++) o = fmaf(fch[j], fc2w[j * 2 + tid], o);
    out[g * 2 + tid] = o;
  }
}

extern "C" void kernel_launch(void* const* d_in, const int* in_sizes, int n_in,
                              void* d_out, int out_size, void* d_ws, size_t ws_size,
                              hipStream_t stream) {
  (void)d_ws; (void)ws_size; (void)in_sizes; (void)n_in; (void)out_size;
  const float* x     = (const float*)d_in[0];
  const int*   ei    = (const int*)d_in[1];
  const float* eattr = (const float*)d_in[2];
  const float* egw   = (const float*)d_in[4];
  const float* att_s = (const float*)d_in[5];
  const float* att_d = (const float*)d_in[6];
  const float* att_e = (const float*)d_in[7];
  const float* wroot = (const float*)d_in[8];
  const float* wnbr  = (const float*)d_in[9];
  const float* gcb   = (const float*)d_in[10];
  const float* fc1w  = (const float*)d_in[11];
  const float* fc1b  = (const float*)d_in[12];
  const float* fc2w  = (const float*)d_in[13];
  const float* fc2b  = (const float*)d_in[14];
  float* out = (float*)d_out;

  k_mega<<<GN, 1024, 0, stream>>>(x, ei, eattr, egw, att_s, att_d, att_e,
                                  wroot, wnbr, gcb, fc1w, fc1b, fc2w, fc2b, out);
}